// Round 1
// 107.586 us; speedup vs baseline: 1.0040x; 1.0040x over previous
//
#include <hip/hip_runtime.h>

#define B_ 4
#define S_ 512
#define T_ 512
#define D_ 256
#define NSRC (B_ * S_)            // 2048 source rows
#define K2F 2.8853900817779268f   // 2*log2(e): exp2(x*K2F) = e^(2x)

typedef __attribute__((ext_vector_type(8))) short short8;   // 8 bf16
typedef __attribute__((ext_vector_type(4))) float f32x4;
typedef __attribute__((ext_vector_type(2))) float f32x2;

__device__ __forceinline__ unsigned short f2bf(float f) {
    union { float f; unsigned u; } v; v.f = f;
    unsigned r = v.u + 0x7FFF + ((v.u >> 16) & 1);   // RNE
    return (unsigned short)(r >> 16);
}

// ---------------------------------------------------------------------------
// K1: prep (shrunk). blocks 0..31: W -> WT bf16 via LDS 64x64 tile transpose.
//     blocks 32..543: prob = softmax(target @ W_prob + b_prob).
// The f32->bf16 cast of src/tgt moved INTO mega (in-register, producers),
// deleting 1024 blocks here and the 2MB abf write + 2MB re-read.
// ---------------------------------------------------------------------------
__global__ __launch_bounds__(256) void prep_kernel(
    const float* __restrict__ tgt,
    const float* __restrict__ Wsrc, const float* __restrict__ Wtgt,
    const float* __restrict__ Wp, const float* __restrict__ bp,
    unsigned short* __restrict__ wtb, float* __restrict__ out)
{
    __shared__ float tl[64 * 65];
    const int blk = blockIdx.x, tid = threadIdx.x;

    if (blk < 32) {
        int wb = blk;
        int e = wb >> 4, ti = wb & 15, tr = ti >> 2, tc = ti & 3;
        int r0 = tr * 64, c0 = tc * 64;
        const float* W = e ? Wtgt : Wsrc;
        #pragma unroll
        for (int it = 0; it < 4; it++) {
            int rr = (tid >> 4) + it * 16;
            int cc = (tid & 15) * 4;
            float4 v = *(const float4*)&W[(r0 + rr) * D_ + c0 + cc];
            tl[(cc + 0) * 65 + rr] = v.x;
            tl[(cc + 1) * 65 + rr] = v.y;
            tl[(cc + 2) * 65 + rr] = v.z;
            tl[(cc + 3) * 65 + rr] = v.w;
        }
        __syncthreads();
        #pragma unroll
        for (int it = 0; it < 2; it++) {
            int jj = (tid >> 3) + it * 32;
            int kk = (tid & 7) * 8;
            ushort4 lo, hi;
            lo.x = f2bf(tl[jj * 65 + kk + 0]); lo.y = f2bf(tl[jj * 65 + kk + 1]);
            lo.z = f2bf(tl[jj * 65 + kk + 2]); lo.w = f2bf(tl[jj * 65 + kk + 3]);
            hi.x = f2bf(tl[jj * 65 + kk + 4]); hi.y = f2bf(tl[jj * 65 + kk + 5]);
            hi.z = f2bf(tl[jj * 65 + kk + 6]); hi.w = f2bf(tl[jj * 65 + kk + 7]);
            int idx = (e * 256 + c0 + jj) * D_ + r0 + kk;
            *(ushort4*)&wtb[idx] = lo;
            *(ushort4*)&wtb[idx + 4] = hi;
        }
    } else {
        int row  = (blk - 32) * 4 + (tid >> 6);
        int lane = tid & 63;
        float p0 = 0.f, p1 = 0.f;
        #pragma unroll
        for (int i = 0; i < 4; i++) {
            int d = lane + i * 64;
            float v = tgt[row * D_ + d];
            float2 w = *(const float2*)&Wp[d * 2];
            p0 = fmaf(v, w.x, p0);
            p1 = fmaf(v, w.y, p1);
        }
        #pragma unroll
        for (int off = 32; off > 0; off >>= 1) {
            p0 += __shfl_down(p0, off, 64);
            p1 += __shfl_down(p1, off, 64);
        }
        if (lane == 0) {
            const float L2E = 1.4426950408889634f;
            float l0 = p0 + bp[0], l1 = p1 + bp[1];
            float e10 = __builtin_amdgcn_exp2f((l1 - l0) * L2E);
            float e01 = __builtin_amdgcn_exp2f((l0 - l1) * L2E);
            out[B_ * T_ * S_ + row * 2 + 0] = __builtin_amdgcn_rcpf(1.f + e10);
            out[B_ * T_ * S_ + row * 2 + 1] = __builtin_amdgcn_rcpf(1.f + e01);
        }
    }
}

// ---------------------------------------------------------------------------
// K2: mega v10 — v9 structure + (a) in-register f32->bf16 A-fragment cast
// (no abf buffer), (b) EIGHT-term rcp folding in consumers:
//   sum_{k=0..7} w_k/dd_k = num/den with
//   den = prod dd_k (pairwise tree), num = pairwise-tree of
//   u_{2i,2i+1} = w_{2i}*dd_{2i+1} + w_{2i+1}*dd_{2i}.
// Per 16 lane-terms: 30 pk-f32 + 2 rcp (vs 28 pk + 4 rcp) = -13.6% issue,
// and halves consumer trans-pipe load (shared with producer exp2).
// genP = C0 - 2 * sum_d w_d / (1 + ys*yt),  C0 = sum w + b_res.
// ---------------------------------------------------------------------------
#define LSTR 68
__global__ __launch_bounds__(768, 1) void mega_kernel(
    const float* __restrict__ src, const float* __restrict__ tgt,
    const unsigned short* __restrict__ wtb,
    const float* __restrict__ bsrc, const float* __restrict__ btgt,
    const float* __restrict__ Wres, const float* __restrict__ bres,
    float* __restrict__ out)
{
    __shared__ float ls[2][64 * LSTR];   // [buf][d][s]
    __shared__ float lt[2][64 * LSTR];   // [buf][d][t]
    __shared__ float c0s;

    const int tid = threadIdx.x;
    const int lane = tid & 63, w = tid >> 6;
    const int s0 = blockIdx.x * 64;
    const int t0 = blockIdx.y * 64;
    const int b  = blockIdx.z;

    if (w == 0) {
        float s = Wres[lane] + Wres[lane + 64] + Wres[lane + 128] + Wres[lane + 192];
        #pragma unroll
        for (int off = 32; off > 0; off >>= 1) s += __shfl_xor(s, off, 64);
        if (lane == 0) c0s = s + bres[0];
    }

    const bool producer = (w < 4);

    // ---- producer state ----
    const int pw  = w & 3;
    const int mat = pw >> 1;             // 0 = s-mat, 1 = t-mat
    const int rb  = 2 * (pw & 1);        // rowgroup base
    const int n = lane & 15, quad = lane >> 4;
    const float* bias = mat ? btgt : bsrc;
    const unsigned short* wtbase = wtb + mat * 256 * D_;

    short8 af[2][8];
    if (producer) {
        const float* xb = mat ? &tgt[(b * T_ + t0) * D_] : &src[(b * S_ + s0) * D_];
        #pragma unroll
        for (int rg = 0; rg < 2; rg++)
            #pragma unroll
            for (int ks = 0; ks < 8; ks++) {
                const float* p = &xb[((rb + rg) * 16 + n) * D_ + ks * 32 + quad * 8];
                float4 u0 = *(const float4*)p;
                float4 u1 = *(const float4*)(p + 4);
                short8 v;
                v[0] = (short)f2bf(u0.x); v[1] = (short)f2bf(u0.y);
                v[2] = (short)f2bf(u0.z); v[3] = (short)f2bf(u0.w);
                v[4] = (short)f2bf(u1.x); v[5] = (short)f2bf(u1.y);
                v[6] = (short)f2bf(u1.z); v[7] = (short)f2bf(u1.w);
                af[rg][ks] = v;
            }
    }

    auto phaseA = [&](int c, int bi) {
        float* lx = (mat ? lt[bi] : ls[bi]);
        #pragma unroll
        for (int cg = 0; cg < 4; cg++) {
            const int gcol = c * 4 + cg;
            const unsigned short* bptr = &wtbase[(gcol * 16 + n) * D_ + quad * 8];
            short8 bf[8];
            #pragma unroll
            for (int ks = 0; ks < 8; ks++) bf[ks] = *(const short8*)&bptr[ks * 32];
            const int dloc = cg * 16 + n;
            const float bv = bias[gcol * 16 + n];
            #pragma unroll
            for (int rg = 0; rg < 2; rg++) {
                f32x4 a4 = {0.f, 0.f, 0.f, 0.f};
                #pragma unroll
                for (int ks = 0; ks < 8; ks++)
                    a4 = __builtin_amdgcn_mfma_f32_16x16x32_bf16(af[rg][ks], bf[ks], a4, 0, 0, 0);
                float4 o;
                o.x = __builtin_amdgcn_exp2f((a4[0] + bv) * K2F);
                o.y = __builtin_amdgcn_exp2f((a4[1] + bv) * K2F);
                o.z = __builtin_amdgcn_exp2f((a4[2] + bv) * K2F);
                o.w = __builtin_amdgcn_exp2f((a4[3] + bv) * K2F);
                *(float4*)&lx[dloc * LSTR + (rb + rg) * 16 + quad * 4] = o;
            }
        }
    };

    // ---- consumer state ----
    const int cl = tid - 256;            // 0..511
    const int m = cl & 15;               // s = s0 + 4m..4m+3
    const int g = cl >> 4;               // t = t0 + 2g, 2g+1   (0..31)
    f32x2 acc[2][2];                     // [t-idx i][s-pair jp]
    #pragma unroll
    for (int i = 0; i < 2; i++) {
        acc[i][0] = (f32x2){0.f, 0.f};
        acc[i][1] = (f32x2){0.f, 0.f};
    }

    if (producer) phaseA(0, 0);
    __syncthreads();

    for (int c = 0; c < 4; c++) {
        const int bi = c & 1;
        if (producer) {
            if (c < 3) phaseA(c + 1, bi ^ 1);
        } else {
            const float* lsb = ls[bi];
            const float* ltb = lt[bi];
            const float* wp = &Wres[c * 64];
            const f32x2 one2 = {1.f, 1.f};
            #pragma unroll 2
            for (int kq = 0; kq < 8; kq++) {
                const int d0 = 8 * kq;
                f32x2 ap[8][2];          // [k][s-pair]
                float cc[8][2];          // [k][t-idx]
                f32x2 wv[8];
                #pragma unroll
                for (int k = 0; k < 8; k++) {
                    float4 a4 = *(const float4*)&lsb[(d0 + k) * LSTR + 4 * m];
                    float2 c2 = *(const float2*)&ltb[(d0 + k) * LSTR + 2 * g];
                    ap[k][0] = (f32x2){a4.x, a4.y};
                    ap[k][1] = (f32x2){a4.z, a4.w};
                    cc[k][0] = c2.x; cc[k][1] = c2.y;
                    const float wk = wp[d0 + k];     // uniform s_load
                    wv[k] = (f32x2){wk, wk};
                }
                #pragma unroll
                for (int i = 0; i < 2; i++) {
                    #pragma unroll
                    for (int jp = 0; jp < 2; jp++) {
                        f32x2 dd[8];
                        #pragma unroll
                        for (int k = 0; k < 8; k++) {
                            const f32x2 cs = {cc[k][i], cc[k][i]};
                            dd[k] = ap[k][jp] * cs + one2;   // 1 + ys*yt
                        }
                        f32x2 p01 = dd[0] * dd[1];
                        f32x2 p23 = dd[2] * dd[3];
                        f32x2 p45 = dd[4] * dd[5];
                        f32x2 p67 = dd[6] * dd[7];
                        f32x2 q03 = p01 * p23;
                        f32x2 q47 = p45 * p67;
                        f32x2 den = q03 * q47;
                        f32x2 u01 = dd[1] * wv[0]; u01 = dd[0] * wv[1] + u01;
                        f32x2 u23 = dd[3] * wv[2]; u23 = dd[2] * wv[3] + u23;
                        f32x2 u45 = dd[5] * wv[4]; u45 = dd[4] * wv[5] + u45;
                        f32x2 u67 = dd[7] * wv[6]; u67 = dd[6] * wv[7] + u67;
                        f32x2 n03 = u01 * p23; n03 = u23 * p01 + n03;
                        f32x2 n47 = u45 * p67; n47 = u67 * p45 + n47;
                        f32x2 num = n03 * q47; num = n47 * q03 + num;
                        f32x2 r;
                        r.x = __builtin_amdgcn_rcpf(den.x);
                        r.y = __builtin_amdgcn_rcpf(den.y);
                        acc[i][jp] = num * r + acc[i][jp];
                    }
                }
            }
        }
        __syncthreads();
    }

    if (!producer) {
        const float C0 = c0s;
        #pragma unroll
        for (int i = 0; i < 2; i++) {
            float4 o;
            o.x = C0 - 2.f * acc[i][0].x;
            o.y = C0 - 2.f * acc[i][0].y;
            o.z = C0 - 2.f * acc[i][1].x;
            o.w = C0 - 2.f * acc[i][1].y;
            *(float4*)&out[(b * T_ + t0 + 2 * g + i) * S_ + s0 + 4 * m] = o;
        }
    }
}

extern "C" void kernel_launch(void* const* d_in, const int* in_sizes, int n_in,
                              void* d_out, int out_size, void* d_ws, size_t ws_size,
                              hipStream_t stream) {
    const float* source = (const float*)d_in[0];
    const float* target = (const float*)d_in[1];
    const float* W_src  = (const float*)d_in[2];
    const float* b_src  = (const float*)d_in[3];
    const float* W_tgt  = (const float*)d_in[4];
    const float* b_tgt  = (const float*)d_in[5];
    const float* W_res  = (const float*)d_in[6];
    const float* b_res  = (const float*)d_in[7];
    const float* W_prob = (const float*)d_in[8];
    const float* b_prob = (const float*)d_in[9];
    float* out = (float*)d_out;

    unsigned short* wtb = (unsigned short*)d_ws;    // 2*256*256 bf16 = 256 KB

    prep_kernel<<<544, 256, 0, stream>>>(target, W_src, W_tgt,
                                         W_prob, b_prob, wtb, out);
    mega_kernel<<<dim3(8, 8, 4), 768, 0, stream>>>(source, target, wtb,
                                                   b_src, b_tgt,
                                                   W_res, b_res, out);
}